// Round 8
// baseline (117.477 us; speedup 1.0000x reference)
//
#include <hip/hip_runtime.h>
#include <hip/hip_bf16.h>

// Problem constants (fixed by reference):
//   B=16, L=512, D=C=F=256, K=3, M=2048, EPS=1e-5
#define Bn 16
#define Ln 512
#define Cn 256
#define Fn 256
#define Kn 3
#define Mn 2048

#define NKSTEP 24        // 768 / 32
#define MT 16            // L-rows per conv block -> 512 conv blocks (2/CU: latency overlap)
#define XS_PS 264        // LDS A-slab row stride (bf16 units); 528 B = 33*16
#define NCONVBLK 512
#define NGHALF 1024      // gather blocks per conv kernel (half of the gather each)
// each gather block: 256 thr x 4 float4, stride 262144; 2 x 1024 x 1024 f4 = B*M*C/4

typedef __attribute__((ext_vector_type(8))) short short8;
typedef __attribute__((ext_vector_type(4))) float f32x4;

static __device__ __forceinline__ unsigned short f2bf(float f) {
    unsigned int u = __float_as_uint(f);
    return (unsigned short)((u + 0x7fff + ((u >> 16) & 1)) >> 16);   // RNE
}

// ---------- K1: weight pack (vectorized short8 dest) + duration scan ----------
// blocks 0..15: per-batch cumsum of target -> m->l map (-1 = zero-fill).
// blocks 16..207: pack. bp[((s*16+nt)*64+lane)*8+j] = w[f=nt*16+(lane&15)][d][k],
//   kappa = k*256+d = s*32 + (lane>>4)*8 + j.  One contiguous short8 per thread.
// (bit-identical to rounds 2-4, 6, 7 — all passed)
__global__ __launch_bounds__(256) void pack_scan(
    const float* __restrict__ w1, const float* __restrict__ w2,
    unsigned short* __restrict__ bp1, unsigned short* __restrict__ bp2,
    const int* __restrict__ target, int* __restrict__ map)
{
    __shared__ int ss[256];
    const int blk = blockIdx.x;
    const int t = threadIdx.x;
    if (blk < 16) {
        const int bb = blk;
        int v0 = target[bb * Ln + 2 * t];
        int v1 = target[bb * Ln + 2 * t + 1];
        ss[t] = v0 + v1;
        __syncthreads();
        for (int off = 1; off < 256; off <<= 1) {
            int add = (t >= off) ? ss[t - off] : 0;
            __syncthreads();
            ss[t] += add;
            __syncthreads();
        }
        int S     = ss[t];        // inclusive pair-scan -> cumsum at 2t+1
        int total = ss[255];
        int cs1   = S;
        int cs0   = S - v1;
        int prev0 = cs0 - v0;
        for (int m = prev0; m < cs0; ++m) map[bb * Mn + m] = 2 * t;
        for (int m = cs0;   m < cs1; ++m) map[bb * Mn + m] = 2 * t + 1;
        for (int m = total + t; m < Mn; m += 256) map[bb * Mn + m] = -1;
    } else {
        // 192 blocks * 256 threads = 49152 short8 units (24576 per conv)
        int v = (blk - 16) * 256 + t;
        const float* w = w1;
        unsigned short* bp = bp1;
        if (v >= 24576) { v -= 24576; w = w2; bp = bp2; }
        int lane = v & 63, nt = (v >> 6) & 15, s = v >> 10;
        int f    = nt * 16 + (lane & 15);
        int kap0 = s * 32 + (lane >> 4) * 8;          // 8-aligned -> k fixed over j
        const float* p = w + ((size_t)f * Cn + (kap0 & 255)) * Kn + (kap0 >> 8);
        short8 o;
        #pragma unroll
        for (int j = 0; j < 8; ++j) o[j] = (short)f2bf(p[3 * j]);
        *(short8*)(bp + (size_t)v * 8) = o;
    }
}

// ---------- fused conv1d(K=3,SAME) via MFMA + bias + LayerNorm + ReLU ----------
// r7 structure (116.8 us, passed) with ONE change: MT 32->16, conv grid 256->512
//   -> 2 conv blocks/CU so two independent stage->MFMA->LN chains overlap per CU
//   (r7 ran 1 wave/SIMD: nothing hid the staging latency or the MFMA chain).
//   Per-wave n-width stays 64 cols (r4 lesson: narrowing N doubles LDS A-traffic).
// Gather split across both conv kernels (E4OFF) unchanged from r7.
// Inner loop: proven 2-deep A+B rings, unconditional harmless-reload tail
//   (r5 lesson: the conditional-tail variant failed post-timing checks).
// A-frag (16x16x32): A[m=lane&15][k=(lane>>4)*8+j]; C/D: col=lane&15, row=(lane>>4)*4+reg.
template <bool IS_F32_IN, bool DO_LINEAR, int E4OFF>
__global__ __launch_bounds__(256) void conv_mfma(
    const void* __restrict__ in_,               // (B,L,C) f32 or bf16
    const unsigned short* __restrict__ bp,      // packed weights (bf16 frag order)
    const float* __restrict__ bias,             // (F)
    const float* __restrict__ gamma,            // (F)
    const float* __restrict__ beta,             // (F)
    const float* __restrict__ lw,               // (F)  [DO_LINEAR]
    const float* __restrict__ lb,               // (1)  [DO_LINEAR]
    unsigned short* __restrict__ hout,          // bf16 (B,L,F) [!DO_LINEAR]
    float* __restrict__ dup,                    // (B,L)        [DO_LINEAR]
    const float* __restrict__ gx,               // (B,L,C) f32  [gather]
    const int* __restrict__ gmap,               // (B,M)        [gather]
    float* __restrict__ gout)                   // (B,M,C)      [gather]
{
    __shared__ __align__(16) unsigned short xs[(MT + 2) * XS_PS];  // ~9.3 KB
    __shared__ float2 red[MT][4];                                  // 0.5 KB
    __shared__ float  red2[MT][4];                                 // 0.25 KB

    const int t = threadIdx.x;

    if (blockIdx.x >= NCONVBLK) {
        // ---- length-regulate gather half: out[b,m,:] = (map>=0) ? x[b,map,:] : 0 ----
        // 4 independent float4 per thread (proven r4/r6/r7): batch map loads, then
        // x loads, then stores (memory-level parallelism).
        const int base = (blockIdx.x - NCONVBLK) * 256 + t;   // 0 .. 262143
        int lv[4];
        #pragma unroll
        for (int i = 0; i < 4; ++i)
            lv[i] = gmap[(E4OFF + base + i * 262144) >> 6];
        float4 val[4];
        #pragma unroll
        for (int i = 0; i < 4; ++i) {
            int e4 = E4OFF + base + i * 262144;
            int d4 = e4 & 63;
            int b  = e4 >> 17;                 // bm>>11, bm=e4>>6
            val[i] = make_float4(0.f, 0.f, 0.f, 0.f);
            if (lv[i] >= 0)
                val[i] = *((const float4*)(gx + (size_t)(b * Ln + lv[i]) * Cn) + d4);
        }
        #pragma unroll
        for (int i = 0; i < 4; ++i)
            ((float4*)gout)[E4OFF + base + i * 262144] = val[i];
        return;
    }

    const int b  = blockIdx.x >> 5;          // 32 l-tiles per batch (MT=16)
    const int l0 = (blockIdx.x & 31) * MT;

    // ---- stage input rows [l0-1, l0+16], zero-padded, as bf16 ----
    if (IS_F32_IN) {
        const float* in = (const float*)in_;
        for (int idx = t; idx < (MT + 2) * 64; idx += 256) {   // 64 float4 per row
            int row = idx >> 6;
            int c4  = (idx & 63) * 4;
            int l = l0 + row - 1;
            float4 v = make_float4(0.f, 0.f, 0.f, 0.f);
            if (l >= 0 && l < Ln) v = *(const float4*)&in[((size_t)b * Ln + l) * Cn + c4];
            unsigned int lo = (unsigned int)f2bf(v.x) | ((unsigned int)f2bf(v.y) << 16);
            unsigned int hi = (unsigned int)f2bf(v.z) | ((unsigned int)f2bf(v.w) << 16);
            *(uint2*)&xs[row * XS_PS + c4] = make_uint2(lo, hi);
        }
    } else {
        const unsigned short* in = (const unsigned short*)in_;
        for (int idx = t; idx < (MT + 2) * 32; idx += 256) {   // 32 x (8 bf16) per row
            int row = idx >> 5;
            int c8  = (idx & 31) * 8;
            int l = l0 + row - 1;
            uint4 v = make_uint4(0u, 0u, 0u, 0u);
            if (l >= 0 && l < Ln) v = *(const uint4*)&in[((size_t)b * Ln + l) * Cn + c8];
            *(uint4*)&xs[row * XS_PS + c8] = v;
        }
    }
    __syncthreads();

    const int lane = t & 63;
    const int wv   = t >> 6;      // n-group: cols wv*64 .. wv*64+63
    const int mrow = lane & 15;
    const int q    = lane >> 4;

    f32x4  acc[4] = {};           // 1 m-tile x 4 n-tiles (MT=16)
    short8 bfr[2][4];             // 2-slot ring, loaded 2 steps ahead
    short8 afr[2];

    auto loadB = [&](int s, int slot) {
        const unsigned short* p = bp + (size_t)((s * 16 + wv * 4) * 64 + lane) * 8;
        #pragma unroll
        for (int i = 0; i < 4; ++i)
            bfr[slot][i] = *(const short8*)(p + (size_t)i * 64 * 8);
    };
    auto loadA = [&](int s, int slot) {
        const int k    = s >> 3;
        const int dcol = (s & 7) * 32 + q * 8;
        afr[slot] = *(const short8*)&xs[(mrow + k) * XS_PS + dcol];
    };

    loadB(0, 0); loadA(0, 0);
    loadB(1, 1); loadA(1, 1);

    #pragma unroll 2
    for (int s = 0; s < NKSTEP; ++s) {
        const int slot = s & 1;
        #pragma unroll
        for (int i = 0; i < 4; ++i)
            acc[i] = __builtin_amdgcn_mfma_f32_16x16x32_bf16(
                afr[slot], bfr[slot][i], acc[i], 0, 0, 0);
        const int sn = (s + 2 < NKSTEP) ? (s + 2) : s;   // tail: harmless reload
        loadB(sn, slot);
        loadA(sn, slot);
    }

    // ---- epilogue: bias + LayerNorm from registers ----
    float gv[4], bv[4], lwv[4], biasv[4];
    #pragma unroll
    for (int i = 0; i < 4; ++i) {
        int col = wv * 64 + i * 16 + mrow;
        biasv[i] = bias[col];
        gv[i]    = gamma[col];
        bv[i]    = beta[col];
        if (DO_LINEAR) lwv[i] = lw[col];
    }
    #pragma unroll
    for (int i = 0; i < 4; ++i)
        #pragma unroll
        for (int r = 0; r < 4; ++r)
            acc[i][r] += biasv[i];

    // per-row partial sums over this wave's 64 cols
    #pragma unroll
    for (int r = 0; r < 4; ++r) {
        float s  = acc[0][r] + acc[1][r] + acc[2][r] + acc[3][r];
        float sq = acc[0][r] * acc[0][r] + acc[1][r] * acc[1][r]
                 + acc[2][r] * acc[2][r] + acc[3][r] * acc[3][r];
        #pragma unroll
        for (int off = 1; off <= 8; off <<= 1) {
            s  += __shfl_xor(s,  off, 64);
            sq += __shfl_xor(sq, off, 64);
        }
        if (mrow == 0) red[q * 4 + r][wv] = make_float2(s, sq);
    }
    __syncthreads();

    float muv[4], rsv[4];
    #pragma unroll
    for (int r = 0; r < 4; ++r) {
        int row = q * 4 + r;
        float2 p0 = red[row][0], p1 = red[row][1], p2 = red[row][2], p3 = red[row][3];
        float s  = p0.x + p1.x + p2.x + p3.x;
        float sq = p0.y + p1.y + p2.y + p3.y;
        float mu  = s * (1.f / 256.f);
        float var = sq * (1.f / 256.f) - mu * mu;
        muv[r] = mu;
        rsv[r] = rsqrtf(var + 1e-5f);
    }

    if (!DO_LINEAR) {
        // store relu(LN(h)) as bf16
        #pragma unroll
        for (int r = 0; r < 4; ++r) {
            int l = l0 + q * 4 + r;
            size_t base = ((size_t)b * Ln + l) * Fn;
            #pragma unroll
            for (int i = 0; i < 4; ++i) {
                float o = fmaxf((acc[i][r] - muv[r]) * rsv[r] * gv[i] + bv[i], 0.f);
                hout[base + wv * 64 + i * 16 + mrow] = f2bf(o);
            }
        }
    } else {
        // fused linear head: dup = relu( relu(LN(h)) . lw + lb )
        #pragma unroll
        for (int r = 0; r < 4; ++r) {
            float dot = 0.f;
            #pragma unroll
            for (int i = 0; i < 4; ++i) {
                float o = fmaxf((acc[i][r] - muv[r]) * rsv[r] * gv[i] + bv[i], 0.f);
                dot += o * lwv[i];
            }
            #pragma unroll
            for (int off = 1; off <= 8; off <<= 1)
                dot += __shfl_xor(dot, off, 64);
            if (mrow == 0) red2[q * 4 + r][wv] = dot;
        }
        __syncthreads();
        if (t < MT) {
            float d = red2[t][0] + red2[t][1] + red2[t][2] + red2[t][3];
            dup[b * Ln + l0 + t] = fmaxf(d + lb[0], 0.f);
        }
    }
}

extern "C" void kernel_launch(void* const* d_in, const int* in_sizes, int n_in,
                              void* d_out, int out_size, void* d_ws, size_t ws_size,
                              hipStream_t stream) {
    const float* x    = (const float*)d_in[0];
    const int*   targ = (const int*)d_in[1];
    // d_in[2] = mel_max_length (scalar) = 2048, hardcoded
    const float* c1w = (const float*)d_in[3];
    const float* c1b = (const float*)d_in[4];
    const float* g1  = (const float*)d_in[5];
    const float* be1 = (const float*)d_in[6];
    const float* c2w = (const float*)d_in[7];
    const float* c2b = (const float*)d_in[8];
    const float* g2  = (const float*)d_in[9];
    const float* be2 = (const float*)d_in[10];
    const float* lw  = (const float*)d_in[11];
    const float* lb  = (const float*)d_in[12];

    float* out     = (float*)d_out;                       // (B,M,C)
    float* out_dup = out + (size_t)Bn * Mn * Cn;          // (B,L)

    // workspace layout (h1 global round-trip, L2-hot)
    char* ws = (char*)d_ws;
    unsigned short* bp1 = (unsigned short*)ws;                       // 384 KiB
    unsigned short* bp2 = (unsigned short*)(ws + 393216);            // 384 KiB
    unsigned short* h1  = (unsigned short*)(ws + 2 * 393216);        // 4 MiB bf16
    int*            map = (int*)(ws + 2 * 393216 + 4194304);         // 128 KiB

    // K1: weight pack (192 blocks) + duration scan (16 blocks)
    pack_scan<<<208, 256, 0, stream>>>(c1w, c2w, bp1, bp2, targ, map);

    // K2: conv1 (blocks 0..511) + gather first half (blocks 512..1535)
    conv_mfma<true, false, 0><<<NCONVBLK + NGHALF, 256, 0, stream>>>(
        (const void*)x, bp1, c1b, g1, be1, nullptr, nullptr, h1, nullptr,
        x, map, out);

    // K3: conv2 + fused linear head (blocks 0..511) + gather second half
    conv_mfma<false, true, 1048576><<<NCONVBLK + NGHALF, 256, 0, stream>>>(
        (const void*)h1, bp2, c2b, g2, be2, lw, lb, nullptr, out_dup,
        x, map, out);
}